// Round 8
// baseline (207.009 us; speedup 1.0000x reference)
//
#include <hip/hip_runtime.h>
#include <hip/hip_bf16.h>
#include <hip/hip_fp16.h>
#include <stdint.h>

#define B_SIZE 8192
#define D_SIZE 2048
#define C_SIZE 128
#define N_INNER 255
#define N_LEAF 256

// fused gemm geometry
#define GBM 32          // M rows per block
#define BK 32           // K per inner iteration
#define KHALF 1024      // K per kg wave-group
#define KITER (KHALF / BK)   // 32
#define NPADL 260       // padded LDS row stride (floats); 1040B stride -> 2-way bank alias (free), 16B aligned

typedef _Float16 half8 __attribute__((ext_vector_type(8)));
typedef __fp16 pk16x2 __attribute__((ext_vector_type(2)));
typedef float f32x4 __attribute__((ext_vector_type(4)));

__device__ inline uint32_t pkh(float a, float b) {
    pk16x2 h = __builtin_amdgcn_cvt_pkrtz(a, b);
    return __builtin_bit_cast(uint32_t, h);
}
// 8 fp32 -> f16 hi + f16 lo fragments (3-term split: exact to ~2^-22 relative)
__device__ inline void split8(const float4 v0, const float4 v1, half8& hi, half8& lo) {
    pk16x2 a01 = __builtin_amdgcn_cvt_pkrtz(v0.x, v0.y);
    pk16x2 a23 = __builtin_amdgcn_cvt_pkrtz(v0.z, v0.w);
    pk16x2 a45 = __builtin_amdgcn_cvt_pkrtz(v1.x, v1.y);
    pk16x2 a67 = __builtin_amdgcn_cvt_pkrtz(v1.z, v1.w);
    uint4 h = make_uint4(__builtin_bit_cast(uint32_t, a01), __builtin_bit_cast(uint32_t, a23),
                         __builtin_bit_cast(uint32_t, a45), __builtin_bit_cast(uint32_t, a67));
    uint4 l = make_uint4(pkh(v0.x - (float)a01[0], v0.y - (float)a01[1]),
                         pkh(v0.z - (float)a23[0], v0.w - (float)a23[1]),
                         pkh(v1.x - (float)a45[0], v1.y - (float)a45[1]),
                         pkh(v1.z - (float)a67[0], v1.w - (float)a67[1]));
    hi = __builtin_bit_cast(half8, h);
    lo = __builtin_bit_cast(half8, l);
}

// ---------------- K0: softmax over leaf_params rows -> Q, logQt (transposed) ----------------
__global__ __launch_bounds__(128) void softmax_kernel(
    const float* __restrict__ lp, float* __restrict__ Q, float* __restrict__ logQt)
{
    int row = blockIdx.x;      // leaf
    int t = threadIdx.x;       // class
    __shared__ float red[128];
    float v = lp[row * C_SIZE + t];
    red[t] = v; __syncthreads();
    for (int s = 64; s > 0; s >>= 1) { if (t < s) red[t] = fmaxf(red[t], red[t + s]); __syncthreads(); }
    float mx = red[0]; __syncthreads();
    float e = expf(v - mx);
    red[t] = e; __syncthreads();
    for (int s = 64; s > 0; s >>= 1) { if (t < s) red[t] += red[t + s]; __syncthreads(); }
    float sum = red[0];
    Q[row * C_SIZE + t] = e / sum;
    logQt[(size_t)t * N_LEAF + row] = (v - mx) - logf(sum);   // [class][leaf]
}

// ---------------- K1: FUSED gemm + sigmoid + tree path + penalties + loss + argmax ----------------
// 256 blocks x 512 thr (8 waves = 2 kg x 4 nw). Wave: 32M x 64N x 1024K.
// K-loop: no LDS, no barriers; fp32 fragment loads + in-register f16 split + MFMA.
// Epilogue: acc -> LDS z[kg], one barrier, per-wave path logic on 4 rows, block atomics.
__global__ __launch_bounds__(512, 2) void fused_kernel(
    const float* __restrict__ x, const float* __restrict__ W,
    const float* __restrict__ bvec, const float* __restrict__ beta,
    const float* __restrict__ Q, const float* __restrict__ logQt,
    const int* __restrict__ target,
    float* __restrict__ g_num, float* __restrict__ g_den, float* __restrict__ g_loss,
    float* __restrict__ out)
{
    __shared__ __align__(16) float zbuf[2][GBM][NPADL];   // 66.6 KB
    __shared__ float s_num[128], s_den[128], s_loss;

    const int t = threadIdx.x;
    const int lane = t & 63, w = t >> 6;
    const int kg = w >> 2, nw = w & 3;
    const int lr = lane & 15, lq = lane >> 4;
    const int m0 = blockIdx.x * GBM;
    const int kb0 = kg * KHALF;

    if (t < 128) s_num[t] = 0.f;
    else if (t < 256) s_den[t - 128] = 0.f;
    if (t == 0) s_loss = 0.f;

    f32x4 acc[2][4];
    #pragma unroll
    for (int mt = 0; mt < 2; ++mt)
        #pragma unroll
        for (int nt = 0; nt < 4; ++nt) acc[mt][nt] = (f32x4){0.f, 0.f, 0.f, 0.f};

    // fragment-pattern fp32 loads: A[m=lr][k=lq*8..+7], B[n=lr][k=lq*8..+7]
    float4 aA[4], bA[8], aB[4], bB[8];

    #define LOAD_A(dst, kb)                                                            \
        _Pragma("unroll")                                                              \
        for (int mt = 0; mt < 2; ++mt) {                                               \
            const float* base = x + (size_t)(m0 + mt * 16 + lr) * D_SIZE + (kb) + lq * 8; \
            dst[mt * 2 + 0] = *(const float4*)base;                                    \
            dst[mt * 2 + 1] = *(const float4*)(base + 4);                              \
        }
    #define LOAD_B(dst, kb)                                                            \
        _Pragma("unroll")                                                              \
        for (int nt = 0; nt < 4; ++nt) {                                               \
            int row = nw * 64 + nt * 16 + lr;                                          \
            bool ok = row < N_INNER;                                                   \
            const float* base = W + (size_t)(ok ? row : 0) * D_SIZE + (kb) + lq * 8;   \
            float4 v0 = *(const float4*)base;                                          \
            float4 v1 = *(const float4*)(base + 4);                                    \
            if (!ok) { v0 = make_float4(0.f,0.f,0.f,0.f); v1 = v0; }                   \
            dst[nt * 2 + 0] = v0; dst[nt * 2 + 1] = v1;                                \
        }
    #define GEMM_STEP(cur_a, cur_b, nxt_a, nxt_b, kbn)                                 \
        {                                                                              \
            LOAD_A(nxt_a, kbn); LOAD_B(nxt_b, kbn);                                    \
            half8 ah[2], al[2], bh[4], bl[4];                                          \
            _Pragma("unroll")                                                          \
            for (int mt = 0; mt < 2; ++mt) split8(cur_a[mt*2], cur_a[mt*2+1], ah[mt], al[mt]); \
            _Pragma("unroll")                                                          \
            for (int nt = 0; nt < 4; ++nt) split8(cur_b[nt*2], cur_b[nt*2+1], bh[nt], bl[nt]); \
            _Pragma("unroll")                                                          \
            for (int mt = 0; mt < 2; ++mt)                                             \
                _Pragma("unroll")                                                      \
                for (int nt = 0; nt < 4; ++nt) {                                       \
                    acc[mt][nt] = __builtin_amdgcn_mfma_f32_16x16x32_f16(ah[mt], bh[nt], acc[mt][nt], 0, 0, 0); \
                    acc[mt][nt] = __builtin_amdgcn_mfma_f32_16x16x32_f16(ah[mt], bl[nt], acc[mt][nt], 0, 0, 0); \
                    acc[mt][nt] = __builtin_amdgcn_mfma_f32_16x16x32_f16(al[mt], bh[nt], acc[mt][nt], 0, 0, 0); \
                }                                                                      \
        }

    LOAD_A(aA, kb0); LOAD_B(bA, kb0);
    int kb = kb0;
    #pragma unroll 1
    for (int kt = 0; kt < KITER; kt += 2) {
        int kb1 = kb + BK;
        int kb2 = (kt + 2 < KITER) ? kb + 2 * BK : kb;   // clamp: last prefetch re-reads (discarded)
        GEMM_STEP(aA, bA, aB, bB, kb1);
        GEMM_STEP(aB, bB, aA, bA, kb2);
        kb += 2 * BK;
    }

    // acc -> LDS (C/D layout: col=lane&15, row=(lane>>4)*4+reg)
    #pragma unroll
    for (int mt = 0; mt < 2; ++mt)
        #pragma unroll
        for (int nt = 0; nt < 4; ++nt)
            #pragma unroll
            for (int r = 0; r < 4; ++r)
                zbuf[kg][mt * 16 + lq * 4 + r][nw * 64 + nt * 16 + lr] = acc[mt][nt][r];
    __syncthreads();

    // ---- path epilogue: wave w owns local rows 4w..4w+3 ----
    const int c0 = lane * 4;
    float bet[4], bia[4];
    #pragma unroll
    for (int j = 0; j < 4; ++j) {
        int c = c0 + j;
        bet[j] = (c < N_INNER) ? beta[c] : 0.f;
        bia[j] = (c < N_INNER) ? bvec[c] : 0.f;
    }
    float pnum[4] = {0.f, 0.f, 0.f, 0.f};
    float pden[4] = {0.f, 0.f, 0.f, 0.f};
    float loss = 0.f;

    for (int i = 0; i < 4; ++i) {
        int rl = w * 4 + i;
        int r = m0 + rl;
        float4 za = *(const float4*)&zbuf[0][rl][c0];
        float4 zb = *(const float4*)&zbuf[1][rl][c0];
        float zv[4] = {za.x + zb.x, za.y + zb.y, za.z + zb.z, za.w + zb.w};
        float pv[4];
        #pragma unroll
        for (int j = 0; j < 4; ++j) {
            int c = c0 + j;
            pv[j] = (c < N_INNER) ? 1.f / (1.f + expf(-bet[j] * (zv[j] + bia[j]))) : 0.f;
        }
        *(float4*)&zbuf[0][rl][c0] = make_float4(pv[0], pv[1], pv[2], pv[3]);  // in-place p
        asm volatile("s_waitcnt lgkmcnt(0)" ::: "memory");  // wave-private row: own writes visible

        int tg = target[r];
        float4 lq4 = *(const float4*)(logQt + (size_t)tg * N_LEAF + c0);
        float lqa[4] = {lq4.x, lq4.y, lq4.z, lq4.w};
        float lsum = 0.f, bestV = -1.f;
        int bestI = 0;
        #pragma unroll
        for (int j = 0; j < 4; ++j) {
            int leaf = c0 + j;
            float pl = 1.f;
            #pragma unroll
            for (int d = 0; d < 8; ++d) {
                int node = (1 << d) - 1 + (leaf >> (8 - d));
                int bit = (leaf >> (7 - d)) & 1;
                float pvn = zbuf[0][rl][node];
                pl *= bit ? pvn : (1.f - pvn);
            }
            lsum += pl * lqa[j];
            if (pl > bestV) { bestV = pl; bestI = leaf; }  // ascending j keeps lowest tie
        }
        if (lane < 32) {
            #pragma unroll
            for (int j = 0; j < 4; ++j) {
                int c = c0 + j;
                if (c < 127) {
                    int h = c + 1; int d = 31 - __clz(h);
                    float pp = 1.f;
                    for (int e = 0; e < d; ++e) {
                        int ha = h >> (d - e);
                        int bit = (h >> (d - 1 - e)) & 1;
                        float pvn = zbuf[0][rl][ha - 1];
                        pp *= bit ? pvn : (1.f - pvn);
                    }
                    pnum[j] += zbuf[0][rl][c] * pp;
                    pden[j] += pp;
                }
            }
        }
        #pragma unroll
        for (int m = 1; m < 64; m <<= 1) {
            lsum += __shfl_xor(lsum, m, 64);
            float ov = __shfl_xor(bestV, m, 64);
            int   oi = __shfl_xor(bestI, m, 64);
            if (ov > bestV || (ov == bestV && oi < bestI)) { bestV = ov; bestI = oi; }
        }
        loss += lsum;
        out[1 + (size_t)r * C_SIZE + lane]      = Q[bestI * C_SIZE + lane];
        out[1 + (size_t)r * C_SIZE + lane + 64] = Q[bestI * C_SIZE + lane + 64];
    }

    // block-level reduction via LDS atomics, then ONE global atomic per address per block
    if (lane < 32) {
        #pragma unroll
        for (int j = 0; j < 4; ++j) {
            int c = c0 + j;
            if (c < 127) {
                atomicAdd(&s_num[c], pnum[j]);
                atomicAdd(&s_den[c], pden[j]);
            }
        }
    }
    if (lane == 0) atomicAdd(&s_loss, loss);
    __syncthreads();
    if (t < 127)                    atomicAdd(&g_num[t], s_num[t]);
    else if (t >= 128 && t < 255)   atomicAdd(&g_den[t - 128], s_den[t - 128]);
    else if (t == 256)              atomicAdd(g_loss, s_loss);
}

// ---------------- K2: finalize total ----------------
__global__ __launch_bounds__(128) void finalize_kernel(
    const float* __restrict__ g_num, const float* __restrict__ g_den,
    const float* __restrict__ g_loss, float* __restrict__ out)
{
    __shared__ float red[128];
    int t = threadIdx.x;
    float term = 0.f;
    if (t < 127) {
        int d = 31 - __clz(t + 1);
        float lam = 0.1f * exp2f(-(float)(d + 1));
        float pen = g_num[t] / g_den[t];
        term = lam * 0.5f * (logf(pen) + logf(1.f - pen));
    }
    red[t] = term; __syncthreads();
    for (int s = 64; s > 0; s >>= 1) { if (t < s) red[t] += red[t + s]; __syncthreads(); }
    if (t == 0) out[0] = -(g_loss[0] / (float)B_SIZE) - red[0];
}

extern "C" void kernel_launch(void* const* d_in, const int* in_sizes, int n_in,
                              void* d_out, int out_size, void* d_ws, size_t ws_size,
                              hipStream_t stream)
{
    const float* x    = (const float*)d_in[0];
    const int*   tgt  = (const int*)d_in[1];
    const float* W    = (const float*)d_in[2];
    const float* b    = (const float*)d_in[3];
    const float* beta = (const float*)d_in[4];
    const float* lp   = (const float*)d_in[5];
    float* out = (float*)d_out;

    // ws layout (floats): [0:128) g_num, [128:256) g_den, [256] g_loss, pad to 512,
    // Q (256x128), logQt (128x256)
    float* g_acc = (float*)d_ws;
    float* Q     = g_acc + 512;
    float* logQt = Q + (size_t)N_LEAF * C_SIZE;

    (void)hipMemsetAsync(d_ws, 0, 512 * sizeof(float), stream);

    softmax_kernel<<<N_LEAF, 128, 0, stream>>>(lp, Q, logQt);

    fused_kernel<<<B_SIZE / GBM, 512, 0, stream>>>(
        x, W, b, beta, Q, logQt, tgt,
        g_acc, g_acc + 128, g_acc + 256, out);

    finalize_kernel<<<1, 128, 0, stream>>>(g_acc, g_acc + 128, g_acc + 256, out);
}